// Round 1
// baseline (722.092 us; speedup 1.0000x reference)
//
#include <hip/hip_runtime.h>

typedef unsigned short u16;
typedef unsigned int u32;
typedef __bf16 bf16x8 __attribute__((ext_vector_type(8)));
typedef float f32x4 __attribute__((ext_vector_type(4)));

#define NB 2
#define SS 2048
#define EE 2048
#define HH 16
#define HDIM 128
#define WINLEN 256
#define SCALEF 0.08838834764831845f
#define LOG2E 1.4426950408889634f

__device__ __forceinline__ u16 f2bf(float f) {
  u32 u = __builtin_bit_cast(u32, f);
  u32 r = (u + 0x7FFFu + ((u >> 16) & 1u)) >> 16;
  return (u16)r;
}

__device__ __forceinline__ void gld_lds16(const void* g, void* l) {
  __builtin_amdgcn_global_load_lds((const __attribute__((address_space(1))) u32*)g,
                                   (__attribute__((address_space(3))) u32*)l, 16, 0, 0);
}

// ---- cast x (f32) -> bf16, 4 elems/thread ----
__global__ __launch_bounds__(256) void cast_x(const float* __restrict__ x, u16* __restrict__ xb) {
  const int i = blockIdx.x * 256 + threadIdx.x;
  float4 v = ((const float4*)x)[i];
  uint2 o;
  o.x = (u32)f2bf(v.x) | ((u32)f2bf(v.y) << 16);
  o.y = (u32)f2bf(v.z) | ((u32)f2bf(v.w) << 16);
  ((uint2*)xb)[i] = o;
}

// ---- transpose+cast weight: W[k][n] f32 -> Wt[n][k] bf16 (2048x2048) ----
__global__ __launch_bounds__(256) void tcast(const float* __restrict__ W, u16* __restrict__ Wt) {
  __shared__ float t[32][33];
  const int n0 = blockIdx.x * 32, k0 = blockIdx.y * 32;
  const int tx = threadIdx.x & 31, ty = threadIdx.x >> 5;
#pragma unroll
  for (int i = ty; i < 32; i += 8)
    t[i][tx] = W[(size_t)(k0 + i) * EE + n0 + tx];
  __syncthreads();
#pragma unroll
  for (int i = ty; i < 32; i += 8)
    Wt[(size_t)(n0 + i) * EE + k0 + tx] = f2bf(t[tx][i]);
}

// ---- transpose v (b,s,h,hd) -> vt (b,h,hd,s), bf16 ----
__global__ __launch_bounds__(256) void vtrans(const u16* __restrict__ V, u16* __restrict__ Vt) {
  __shared__ u16 t[32][33];
  const int s0 = blockIdx.x * 32, d0 = blockIdx.y * 32;
  const int bh = blockIdx.z;
  const int b = bh >> 4, h = bh & 15;
  const int tx = threadIdx.x & 31, ty = threadIdx.x >> 5;
  const u16* src = V + ((size_t)b * SS) * EE + h * HDIM;
#pragma unroll
  for (int i = ty; i < 32; i += 8)
    t[i][tx] = src[(size_t)(s0 + i) * EE + d0 + tx];
  __syncthreads();
  u16* dst = Vt + (size_t)bh * HDIM * SS;
#pragma unroll
  for (int i = ty; i < 32; i += 8)
    dst[(size_t)(d0 + i) * SS + s0 + tx] = t[tx][i];
}

// ---- GEMM: C[m][n] = sum_k A[m][k]*Bt[n][k] + bias[n]; A,Bt bf16; 128x128 tile ----
__global__ __launch_bounds__(256) void gemm_bt(
    const u16* __restrict__ A, const u16* __restrict__ Bt,
    const float* __restrict__ bias, u16* __restrict__ Cb, float* __restrict__ Cf) {
  __shared__ u16 As[128 * 32];
  __shared__ u16 Bs[128 * 32];
  const int tid = threadIdx.x;
  const int lane = tid & 63;
  const int wv = tid >> 6;
  const int wr = wv >> 1, wc = wv & 1;
  const int fr = lane & 15, fg = lane >> 4;
  const int m0 = blockIdx.x * 128, n0 = blockIdx.y * 128;
  const int srow = tid >> 2;
  const int scol = (tid & 3) * 8;
  f32x4 acc[4][4] = {};
  const u16* pa0 = A + (size_t)(m0 + srow) * 2048 + scol;
  const u16* pa1 = A + (size_t)(m0 + 64 + srow) * 2048 + scol;
  const u16* pb0 = Bt + (size_t)(n0 + srow) * 2048 + scol;
  const u16* pb1 = Bt + (size_t)(n0 + 64 + srow) * 2048 + scol;
  for (int k0 = 0; k0 < 2048; k0 += 32) {
    gld_lds16(pa0 + k0, As + tid * 8);
    gld_lds16(pa1 + k0, As + 2048 + tid * 8);
    gld_lds16(pb0 + k0, Bs + tid * 8);
    gld_lds16(pb1 + k0, Bs + 2048 + tid * 8);
    __syncthreads();
    bf16x8 af[4], bfg[4];
#pragma unroll
    for (int m = 0; m < 4; ++m)
      af[m] = *(const bf16x8*)(As + (wr * 64 + m * 16 + fr) * 32 + fg * 8);
#pragma unroll
    for (int n = 0; n < 4; ++n)
      bfg[n] = *(const bf16x8*)(Bs + (wc * 64 + n * 16 + fr) * 32 + fg * 8);
#pragma unroll
    for (int m = 0; m < 4; ++m)
#pragma unroll
      for (int n = 0; n < 4; ++n)
        acc[m][n] = __builtin_amdgcn_mfma_f32_16x16x32_bf16(af[m], bfg[n], acc[m][n], 0, 0, 0);
    __syncthreads();
  }
#pragma unroll
  for (int m = 0; m < 4; ++m) {
    const int gr0 = m0 + wr * 64 + m * 16 + fg * 4;
#pragma unroll
    for (int n = 0; n < 4; ++n) {
      const int gc = n0 + wc * 64 + n * 16 + fr;
      const float bv = bias[gc];
#pragma unroll
      for (int j = 0; j < 4; ++j) {
        float v = acc[m][n][j] + bv;
        size_t off = (size_t)(gr0 + j) * 2048 + gc;
        if (Cf) Cf[off] = v;
        else Cb[off] = f2bf(v);
      }
    }
  }
}

// ---- flash attention: one wave = 32 q rows; block = 128 q rows of one (b,h) ----
// LOCAL=false: full range with alibi (-|i-j|), distance cutoff 128 (exact in f32).
// LOCAL=true: k restricted to the 256-token chunk, no alibi.
template <bool LOCAL>
__global__ __launch_bounds__(256) void attn_kernel(
    const u16* __restrict__ Q, const u16* __restrict__ K,
    const u16* __restrict__ Vt, u16* __restrict__ O) {
  __shared__ u16 Pt[4][32 * 32];
  const int tid = threadIdx.x;
  const int lane = tid & 63;
  const int wv = tid >> 6;
  const int fr = lane & 15, fg = lane >> 4;
  const int qbase = blockIdx.x * 128;
  const int bh = blockIdx.y;
  const int b = bh >> 4, h = bh & 15;
  const int qw = qbase + wv * 32;
  const size_t rowbase = (size_t)b * SS;

  bf16x8 qf[2][4];
#pragma unroll
  for (int m = 0; m < 2; ++m)
#pragma unroll
    for (int ds = 0; ds < 4; ++ds)
      qf[m][ds] = *(const bf16x8*)(Q + (rowbase + qw + m * 16 + fr) * EE + h * HDIM + ds * 32 + fg * 8);

  f32x4 acc[2][8] = {};
  float mrun[2][4], lrun[2][4];
#pragma unroll
  for (int m = 0; m < 2; ++m)
#pragma unroll
    for (int j = 0; j < 4; ++j) { mrun[m][j] = -1e30f; lrun[m][j] = 0.f; }

  int lo, hi;  // inclusive k-tile range
  if (LOCAL) {
    lo = (qbase >> 8) * (WINLEN / 32);
    hi = lo + (WINLEN / 32) - 1;
  } else {
    lo = (qw - 160) >> 5; if (lo < 0) lo = 0;
    hi = (qw + 191) >> 5; if (hi > SS / 32 - 1) hi = SS / 32 - 1;
  }

  for (int kti = lo; kti <= hi; ++kti) {
    const int kt = kti * 32;
    f32x4 sf[2][2] = {};
#pragma unroll
    for (int ds = 0; ds < 4; ++ds) {
      bf16x8 kf[2];
#pragma unroll
      for (int n = 0; n < 2; ++n)
        kf[n] = *(const bf16x8*)(K + (rowbase + kt + n * 16 + fr) * EE + h * HDIM + ds * 32 + fg * 8);
#pragma unroll
      for (int m = 0; m < 2; ++m)
#pragma unroll
        for (int n = 0; n < 2; ++n)
          sf[m][n] = __builtin_amdgcn_mfma_f32_16x16x32_bf16(qf[m][ds], kf[n], sf[m][n], 0, 0, 0);
    }
    float p[2][2][4];
#pragma unroll
    for (int m = 0; m < 2; ++m) {
      float rmax[4];
#pragma unroll
      for (int j = 0; j < 4; ++j) {
        float s0 = sf[m][0][j] * SCALEF;
        float s1 = sf[m][1][j] * SCALEF;
        if (!LOCAL) {
          const float qr = (float)(qw + m * 16 + fg * 4 + j);
          s0 -= fabsf(qr - (float)(kt + fr));
          s1 -= fabsf(qr - (float)(kt + 16 + fr));
        }
        p[m][0][j] = s0;
        p[m][1][j] = s1;
        float r = fmaxf(s0, s1);
#pragma unroll
        for (int xm = 1; xm < 16; xm <<= 1)
          r = fmaxf(r, __shfl_xor(r, xm));
        rmax[j] = r;
      }
#pragma unroll
      for (int j = 0; j < 4; ++j) {
        const float mold = mrun[m][j];
        const float mnew = fmaxf(mold, rmax[j]);
        const float corr = exp2f((mold - mnew) * LOG2E);
        mrun[m][j] = mnew;
        const float p0 = exp2f((p[m][0][j] - mnew) * LOG2E);
        const float p1 = exp2f((p[m][1][j] - mnew) * LOG2E);
        p[m][0][j] = p0;
        p[m][1][j] = p1;
        float rs = p0 + p1;
#pragma unroll
        for (int xm = 1; xm < 16; xm <<= 1)
          rs += __shfl_xor(rs, xm);
        lrun[m][j] = lrun[m][j] * corr + rs;
#pragma unroll
        for (int n = 0; n < 8; ++n) acc[m][n][j] *= corr;
      }
#pragma unroll
      for (int n = 0; n < 2; ++n)
#pragma unroll
        for (int j = 0; j < 4; ++j)
          Pt[wv][(m * 16 + fg * 4 + j) * 32 + n * 16 + fr] = f2bf(p[m][n][j]);
    }
    asm volatile("s_waitcnt lgkmcnt(0)" ::: "memory");
    bf16x8 ap[2];
#pragma unroll
    for (int m = 0; m < 2; ++m)
      ap[m] = *(const bf16x8*)(&Pt[wv][(m * 16 + fr) * 32 + fg * 8]);
#pragma unroll
    for (int n = 0; n < 8; ++n) {
      const bf16x8 vf = *(const bf16x8*)(Vt + ((size_t)bh * HDIM + n * 16 + fr) * SS + kt + fg * 8);
#pragma unroll
      for (int m = 0; m < 2; ++m)
        acc[m][n] = __builtin_amdgcn_mfma_f32_16x16x32_bf16(ap[m], vf, acc[m][n], 0, 0, 0);
    }
  }
#pragma unroll
  for (int m = 0; m < 2; ++m)
#pragma unroll
    for (int n = 0; n < 8; ++n)
#pragma unroll
      for (int j = 0; j < 4; ++j) {
        const int qr = qw + m * 16 + fg * 4 + j;
        const float v = acc[m][n][j] / lrun[m][j];
        O[(rowbase + qr) * EE + h * HDIM + n * 16 + fr] = f2bf(v);
      }
}

// ---- mix: ctx = mask ? ctx_global : ctx_local (per token row) ----
__global__ __launch_bounds__(256) void mix_kernel(
    const u16* __restrict__ cg, const u16* __restrict__ cl,
    const int* __restrict__ mask, u16* __restrict__ ctx) {
  const size_t i = (size_t)blockIdx.x * 256 + threadIdx.x;  // 8-elem group
  const size_t base = i * 8;
  const int row = (int)(base >> 11);  // /2048
  const u16* src = (mask[row] == 1) ? cg : cl;
  *(uint4*)(ctx + base) = *(const uint4*)(src + base);
}

extern "C" void kernel_launch(void* const* d_in, const int* in_sizes, int n_in,
                              void* d_out, int out_size, void* d_ws, size_t ws_size,
                              hipStream_t stream) {
  (void)in_sizes; (void)n_in; (void)out_size; (void)ws_size;
  const float* x = (const float*)d_in[0];
  const int* gmask = (const int*)d_in[1];
  const float* Wq = (const float*)d_in[2];   const float* bq = (const float*)d_in[3];
  const float* Wk = (const float*)d_in[4];   const float* bk = (const float*)d_in[5];
  const float* Wv = (const float*)d_in[6];   const float* bv = (const float*)d_in[7];
  const float* Wlq = (const float*)d_in[8];  const float* blq = (const float*)d_in[9];
  const float* Wlk = (const float*)d_in[10]; const float* blk = (const float*)d_in[11];
  const float* Wlv = (const float*)d_in[12]; const float* blv = (const float*)d_in[13];
  const float* Wp = (const float*)d_in[14];  const float* bp = (const float*)d_in[15];
  float* out = (float*)d_out;

  // workspace layout (16 MiB stride per slot; 184 MiB total)
  char* w = (char*)d_ws;
  u16* xb   = (u16*)(w + (size_t)0);
  u16* wt   = (u16*)(w + ((size_t)16 << 20));  // reused 8 MiB weight slot
  u16* qB   = (u16*)(w + ((size_t)24 << 20));
  u16* kB   = (u16*)(w + ((size_t)40 << 20));
  u16* vB   = (u16*)(w + ((size_t)56 << 20));
  u16* lqB  = (u16*)(w + ((size_t)72 << 20));
  u16* lkB  = (u16*)(w + ((size_t)88 << 20));
  u16* lvB  = (u16*)(w + ((size_t)104 << 20));
  u16* vtB  = (u16*)(w + ((size_t)120 << 20));
  u16* lvtB = (u16*)(w + ((size_t)136 << 20));
  u16* cgB  = (u16*)(w + ((size_t)152 << 20));
  u16* clB  = (u16*)(w + ((size_t)168 << 20));

  cast_x<<<8192, 256, 0, stream>>>(x, xb);

  const float* Ws[6] = {Wq, Wk, Wv, Wlq, Wlk, Wlv};
  const float* bs[6] = {bq, bk, bv, blq, blk, blv};
  u16* outs[6] = {qB, kB, vB, lqB, lkB, lvB};
  for (int i = 0; i < 6; ++i) {
    tcast<<<dim3(64, 64), 256, 0, stream>>>(Ws[i], wt);
    gemm_bt<<<dim3(32, 16), 256, 0, stream>>>(xb, wt, bs[i], outs[i], nullptr);
  }

  vtrans<<<dim3(64, 4, 32), 256, 0, stream>>>(vB, vtB);
  vtrans<<<dim3(64, 4, 32), 256, 0, stream>>>(lvB, lvtB);

  attn_kernel<false><<<dim3(16, 32), 256, 0, stream>>>(qB, kB, vtB, cgB);
  attn_kernel<true><<<dim3(16, 32), 256, 0, stream>>>(lqB, lkB, lvtB, clB);

  mix_kernel<<<4096, 256, 0, stream>>>(cgB, clB, gmask, xb);  // ctx -> xb slot

  tcast<<<dim3(64, 64), 256, 0, stream>>>(Wp, wt);
  gemm_bt<<<dim3(32, 16), 256, 0, stream>>>(xb, wt, bp, nullptr, out);
}

// Round 2
// 664.073 us; speedup vs baseline: 1.0874x; 1.0874x over previous
//
#include <hip/hip_runtime.h>

typedef unsigned short u16;
typedef unsigned int u32;
typedef __bf16 bf16x8 __attribute__((ext_vector_type(8)));
typedef float f32x4 __attribute__((ext_vector_type(4)));

#define NB 2
#define SS 2048
#define EE 2048
#define HH 16
#define HDIM 128
#define WINLEN 256
#define SCALEF 0.08838834764831845f
#define LOG2E 1.4426950408889634f

__device__ __forceinline__ u16 f2bf(float f) {
  u32 u = __builtin_bit_cast(u32, f);
  u32 r = (u + 0x7FFFu + ((u >> 16) & 1u)) >> 16;
  return (u16)r;
}

__device__ __forceinline__ void gld_lds16(const void* g, void* l) {
  __builtin_amdgcn_global_load_lds((const __attribute__((address_space(1))) u32*)g,
                                   (__attribute__((address_space(3))) u32*)l, 16, 0, 0);
}

// ---- cast x (f32) -> bf16, 4 elems/thread ----
__global__ __launch_bounds__(256) void cast_x(const float* __restrict__ x, u16* __restrict__ xb) {
  const int i = blockIdx.x * 256 + threadIdx.x;
  float4 v = ((const float4*)x)[i];
  uint2 o;
  o.x = (u32)f2bf(v.x) | ((u32)f2bf(v.y) << 16);
  o.y = (u32)f2bf(v.z) | ((u32)f2bf(v.w) << 16);
  ((uint2*)xb)[i] = o;
}

// ---- transpose+cast one 2048x2048 weight: W[k][n] f32 -> Wt[n][k] bf16 ----
__device__ __forceinline__ void tcast_body(const float* __restrict__ W, u16* __restrict__ Wt,
                                           int n0, int k0, int tx, int ty) {
  __shared__ float t[32][33];
#pragma unroll
  for (int i = ty; i < 32; i += 8)
    t[i][tx] = W[(size_t)(k0 + i) * EE + n0 + tx];
  __syncthreads();
#pragma unroll
  for (int i = ty; i < 32; i += 8)
    Wt[(size_t)(n0 + i) * EE + k0 + tx] = f2bf(t[tx][i]);
}

__global__ __launch_bounds__(256) void tcast(const float* __restrict__ W, u16* __restrict__ Wt) {
  tcast_body(W, Wt, blockIdx.x * 32, blockIdx.y * 32, threadIdx.x & 31, threadIdx.x >> 5);
}

__global__ __launch_bounds__(256) void tcast6(
    const float* __restrict__ W0, const float* __restrict__ W1, const float* __restrict__ W2,
    const float* __restrict__ W3, const float* __restrict__ W4, const float* __restrict__ W5,
    u16* __restrict__ dst) {
  const float* Ws[6] = {W0, W1, W2, W3, W4, W5};
  tcast_body(Ws[blockIdx.z], dst + (size_t)blockIdx.z * EE * EE,
             blockIdx.x * 32, blockIdx.y * 32, threadIdx.x & 31, threadIdx.x >> 5);
}

// ---- transpose v (b,s,h,hd) -> vt (b,h,hd,s), bf16 ----
__global__ __launch_bounds__(256) void vtrans(const u16* __restrict__ V, u16* __restrict__ Vt) {
  __shared__ u16 t[32][33];
  const int s0 = blockIdx.x * 32, d0 = blockIdx.y * 32;
  const int bh = blockIdx.z;
  const int b = bh >> 4, h = bh & 15;
  const int tx = threadIdx.x & 31, ty = threadIdx.x >> 5;
  const u16* src = V + ((size_t)b * SS) * EE + h * HDIM;
#pragma unroll
  for (int i = ty; i < 32; i += 8)
    t[i][tx] = src[(size_t)(s0 + i) * EE + d0 + tx];
  __syncthreads();
  u16* dst = Vt + (size_t)bh * HDIM * SS;
#pragma unroll
  for (int i = ty; i < 32; i += 8)
    dst[(size_t)(d0 + i) * SS + s0 + tx] = t[tx][i];
}

// ---- GEMM: C[m][n] = sum_k A[m][k]*Bt[n][k] + bias[n]; 128x128 tile, m97 structure ----
// MODE 0: bf16 out, N split across six 4096x2048 buffers (contiguous, 1<<23 elems each)
// MODE 1: f32 out, flat [4096][2048]
template <int MODE>
__global__ __launch_bounds__(256) void gemm_bt(
    const u16* __restrict__ A, const u16* __restrict__ Bt,
    const float* __restrict__ bias, void* __restrict__ Cout) {
  __shared__ u16 As[128 * 32];
  __shared__ u16 Bs[128 * 32];
  const int tid = threadIdx.x;
  const int lane = tid & 63;
  const int wv = tid >> 6;
  const int wr = wv >> 1, wc = wv & 1;
  const int fr = lane & 15, fg = lane >> 4;
  // XCD-aware swizzle (grid size divisible by 8)
  int lin = blockIdx.y * gridDim.x + blockIdx.x;
  const int nwg = gridDim.x * gridDim.y;
  lin = (lin & 7) * (nwg >> 3) + (lin >> 3);
  const int m0 = (lin % gridDim.x) * 128, n0 = (lin / gridDim.x) * 128;
  const int srow = tid >> 2;
  const int scol = (tid & 3) * 8;
  f32x4 acc[4][4] = {};
  const u16* pa0 = A + (size_t)(m0 + srow) * 2048 + scol;
  const u16* pa1 = A + (size_t)(m0 + 64 + srow) * 2048 + scol;
  const u16* pb0 = Bt + (size_t)(n0 + srow) * 2048 + scol;
  const u16* pb1 = Bt + (size_t)(n0 + 64 + srow) * 2048 + scol;
  for (int k0 = 0; k0 < 2048; k0 += 32) {
    gld_lds16(pa0 + k0, As + tid * 8);
    gld_lds16(pa1 + k0, As + 2048 + tid * 8);
    gld_lds16(pb0 + k0, Bs + tid * 8);
    gld_lds16(pb1 + k0, Bs + 2048 + tid * 8);
    __syncthreads();
    bf16x8 af[4], bfg[4];
#pragma unroll
    for (int m = 0; m < 4; ++m)
      af[m] = *(const bf16x8*)(As + (wr * 64 + m * 16 + fr) * 32 + fg * 8);
#pragma unroll
    for (int n = 0; n < 4; ++n)
      bfg[n] = *(const bf16x8*)(Bs + (wc * 64 + n * 16 + fr) * 32 + fg * 8);
#pragma unroll
    for (int m = 0; m < 4; ++m)
#pragma unroll
      for (int n = 0; n < 4; ++n)
        acc[m][n] = __builtin_amdgcn_mfma_f32_16x16x32_bf16(af[m], bfg[n], acc[m][n], 0, 0, 0);
    __syncthreads();
  }
#pragma unroll
  for (int m = 0; m < 4; ++m) {
    const int gr0 = m0 + wr * 64 + m * 16 + fg * 4;
#pragma unroll
    for (int n = 0; n < 4; ++n) {
      const int gc = n0 + wc * 64 + n * 16 + fr;
      const float bv = bias[gc];
#pragma unroll
      for (int j = 0; j < 4; ++j) {
        float v = acc[m][n][j] + bv;
        if (MODE == 0) {
          size_t off = ((size_t)(gc >> 11) << 23) + (size_t)(gr0 + j) * 2048 + (gc & 2047);
          ((u16*)Cout)[off] = f2bf(v);
        } else {
          ((float*)Cout)[(size_t)(gr0 + j) * 2048 + gc] = v;
        }
      }
    }
  }
}

// ---- flash attention v2: LDS-staged K/V, double-buffered, counted vmcnt ----
// Block = 128 q rows x one (b,h); 4 waves, each owns 32 q rows.
// All waves share a uniform 256-key window (8 tiles of 32):
//   GLOBAL: kstart = clamp(qb-64, 0, S-256). Keys outside |q-k|<=64 carry weight
//           <= e^-52 via alibi (exact-in-f32 negligible); extra in-window keys are
//           naturally suppressed, so no masking needed.
//   LOCAL:  kstart = chunk base (the 256-token window itself).
template <bool LOCAL>
__global__ __launch_bounds__(256) void attn_kernel(
    const u16* __restrict__ Q, const u16* __restrict__ K,
    const u16* __restrict__ Vt, u16* __restrict__ O) {
  __shared__ u16 Ks[2][32 * 128];
  __shared__ u16 Vs[2][128 * 32];
  __shared__ u16 Pt[4][32 * 32];
  const int tid = threadIdx.x;
  const int lane = tid & 63;
  const int wv = tid >> 6;
  const int fr = lane & 15, fg = lane >> 4;
  // XCD swizzle: group same-bh blocks on one XCD for K/V L2 reuse
  int lin = blockIdx.y * 16 + blockIdx.x;
  lin = (lin & 7) * 64 + (lin >> 3);
  const int qbase = (lin & 15) * 128;
  const int bh = lin >> 4;
  const int b = bh >> 4, h = bh & 15;
  const int qw = qbase + wv * 32;
  const size_t rowbase = (size_t)b * SS;
  int kstart;
  if (LOCAL) {
    kstart = qbase & ~255;
  } else {
    kstart = qbase - 64;
    if (kstart < 0) kstart = 0;
    if (kstart > SS - 256) kstart = SS - 256;
  }

  // Q fragments (A-operand: lane holds row fr, k-slice ds*32+fg*8)
  bf16x8 qf[2][4];
#pragma unroll
  for (int m = 0; m < 2; ++m)
#pragma unroll
    for (int ds = 0; ds < 4; ++ds)
      qf[m][ds] = *(const bf16x8*)(Q + (rowbase + qw + m * 16 + fr) * EE + h * HDIM + ds * 32 + fg * 8);

  f32x4 acc[2][8] = {};
  float mrun[2][4], lrun[2][4];
#pragma unroll
  for (int m = 0; m < 2; ++m)
#pragma unroll
    for (int j = 0; j < 4; ++j) { mrun[m][j] = -1e30f; lrun[m][j] = 0.f; }

  // staging geometry (XOR-swizzled LDS: pre-swizzled global source, linear dest)
  const u16* Kg = K + (rowbase + kstart) * EE + h * HDIM;
  const u16* Vg = Vt + (size_t)bh * HDIM * SS + kstart;
  const int r0 = tid >> 4;                          // K row 0..15 (+16 for instr1)
  const int kslot = (tid & 15) ^ (r0 & 7);          // inverse st-swizzle, K
  const int d0 = tid >> 2;                          // V row 0..63 (+64)
  const int vslot = (tid & 3) ^ ((tid >> 3) & 3);   // inverse st-swizzle, V

  auto STAGE = [&](int buf, int t) {
    const u16* kg = Kg + (size_t)t * 32 * EE;
    gld_lds16(kg + (size_t)r0 * EE + kslot * 8, &Ks[buf][0] + tid * 8);
    gld_lds16(kg + (size_t)(16 + r0) * EE + kslot * 8, &Ks[buf][2048] + tid * 8);
    const u16* vg = Vg + t * 32;
    gld_lds16(vg + (size_t)d0 * SS + vslot * 8, &Vs[buf][0] + tid * 8);
    gld_lds16(vg + (size_t)(64 + d0) * SS + vslot * 8, &Vs[buf][2048] + tid * 8);
  };

  const float C1 = SCALEF * LOG2E;

  STAGE(0, 0);
  for (int t = 0; t < 8; ++t) {
    const int buf = t & 1;
    if (t < 7) {
      STAGE(buf ^ 1, t + 1);
      asm volatile("s_waitcnt vmcnt(4)" ::: "memory");
    } else {
      asm volatile("s_waitcnt vmcnt(0)" ::: "memory");
    }
    __builtin_amdgcn_s_barrier();

    const int kt = kstart + t * 32;
    f32x4 sf[2][2] = {};
#pragma unroll
    for (int ds = 0; ds < 4; ++ds) {
      bf16x8 kf[2];
#pragma unroll
      for (int n = 0; n < 2; ++n)
        kf[n] = *(const bf16x8*)(&Ks[buf][(n * 16 + fr) * 128 + ((ds * 32 + fg * 8) ^ ((fr & 7) * 8))]);
#pragma unroll
      for (int m = 0; m < 2; ++m)
#pragma unroll
        for (int n = 0; n < 2; ++n)
          sf[m][n] = __builtin_amdgcn_mfma_f32_16x16x32_bf16(qf[m][ds], kf[n], sf[m][n], 0, 0, 0);
    }
    float p[2][2][4];
#pragma unroll
    for (int m = 0; m < 2; ++m) {
      float rmax[4];
#pragma unroll
      for (int j = 0; j < 4; ++j) {
        float s0 = sf[m][0][j] * C1;  // log2 domain
        float s1 = sf[m][1][j] * C1;
        if (!LOCAL) {
          const float qr = (float)(qw + m * 16 + fg * 4 + j);
          s0 -= fabsf(qr - (float)(kt + fr)) * LOG2E;
          s1 -= fabsf(qr - (float)(kt + 16 + fr)) * LOG2E;
        }
        p[m][0][j] = s0;
        p[m][1][j] = s1;
        float r = fmaxf(s0, s1);
#pragma unroll
        for (int xm = 1; xm < 16; xm <<= 1)
          r = fmaxf(r, __shfl_xor(r, xm));
        rmax[j] = r;
      }
#pragma unroll
      for (int j = 0; j < 4; ++j) {
        const float mold = mrun[m][j];
        const float mnew = fmaxf(mold, rmax[j]);
        const float corr = exp2f(mold - mnew);
        mrun[m][j] = mnew;
        const float p0 = exp2f(p[m][0][j] - mnew);
        const float p1 = exp2f(p[m][1][j] - mnew);
        p[m][0][j] = p0;
        p[m][1][j] = p1;
        float rs = p0 + p1;
#pragma unroll
        for (int xm = 1; xm < 16; xm <<= 1)
          rs += __shfl_xor(rs, xm);
        lrun[m][j] = lrun[m][j] * corr + rs;
#pragma unroll
        for (int n = 0; n < 8; ++n) acc[m][n][j] *= corr;
      }
#pragma unroll
      for (int n = 0; n < 2; ++n)
#pragma unroll
        for (int j = 0; j < 4; ++j)
          Pt[wv][(m * 16 + fg * 4 + j) * 32 + n * 16 + fr] = f2bf(p[m][n][j]);
    }
    asm volatile("s_waitcnt lgkmcnt(0)" ::: "memory");
    bf16x8 ap[2];
#pragma unroll
    for (int m = 0; m < 2; ++m)
      ap[m] = *(const bf16x8*)(&Pt[wv][(m * 16 + fr) * 32 + fg * 8]);
#pragma unroll
    for (int n = 0; n < 8; ++n) {
      const bf16x8 vf = *(const bf16x8*)(&Vs[buf][(n * 16 + fr) * 32 + ((fg * 8) ^ (((fr >> 1) & 3) * 8))]);
#pragma unroll
      for (int m = 0; m < 2; ++m)
        acc[m][n] = __builtin_amdgcn_mfma_f32_16x16x32_bf16(ap[m], vf, acc[m][n], 0, 0, 0);
    }
    __builtin_amdgcn_s_barrier();
  }
#pragma unroll
  for (int m = 0; m < 2; ++m)
#pragma unroll
    for (int n = 0; n < 8; ++n)
#pragma unroll
      for (int j = 0; j < 4; ++j) {
        const int qr = qw + m * 16 + fg * 4 + j;
        const float v = acc[m][n][j] / lrun[m][j];
        O[(rowbase + qr) * EE + h * HDIM + n * 16 + fr] = f2bf(v);
      }
}

// ---- mix: ctx = mask ? ctx_global : ctx_local (per token row) ----
__global__ __launch_bounds__(256) void mix_kernel(
    const u16* __restrict__ cg, const u16* __restrict__ cl,
    const int* __restrict__ mask, u16* __restrict__ ctx) {
  const size_t i = (size_t)blockIdx.x * 256 + threadIdx.x;
  const size_t base = i * 8;
  const int row = (int)(base >> 11);
  const u16* src = (mask[row] == 1) ? cg : cl;
  *(uint4*)(ctx + base) = *(const uint4*)(src + base);
}

extern "C" void kernel_launch(void* const* d_in, const int* in_sizes, int n_in,
                              void* d_out, int out_size, void* d_ws, size_t ws_size,
                              hipStream_t stream) {
  (void)in_sizes; (void)n_in; (void)out_size; (void)ws_size;
  const float* x = (const float*)d_in[0];
  const int* gmask = (const int*)d_in[1];
  const float* Wq = (const float*)d_in[2];   const float* bq = (const float*)d_in[3];
  const float* Wk = (const float*)d_in[4];   const float* bk = (const float*)d_in[5];
  const float* Wv = (const float*)d_in[6];   const float* bv = (const float*)d_in[7];
  const float* Wlq = (const float*)d_in[8];  const float* blq = (const float*)d_in[9];
  const float* Wlk = (const float*)d_in[10]; const float* blk = (const float*)d_in[11];
  const float* Wlv = (const float*)d_in[12]; const float* blv = (const float*)d_in[13];
  const float* Wp = (const float*)d_in[14];  const float* bp = (const float*)d_in[15];
  float* out = (float*)d_out;

  // ws layout (bytes): [0,16M) xb/ctx; [16M,64M) WtAll (sub-reused: wtP@16M,
  // vtB@32M, lvtB@48M after proj GEMM); [64M,160M) six proj outputs (16M each);
  // [160M,+48K) biasAll.
  char* w = (char*)d_ws;
  u16* xb    = (u16*)(w);
  u16* WtAll = (u16*)(w + ((size_t)16 << 20));
  u16* wtP   = (u16*)(w + ((size_t)16 << 20));
  u16* vtB   = (u16*)(w + ((size_t)32 << 20));
  u16* lvtB  = (u16*)(w + ((size_t)48 << 20));
  u16* projout = (u16*)(w + ((size_t)64 << 20));
  u16* qB  = projout;
  u16* kB  = projout + ((size_t)1 << 23);
  u16* vB  = projout + ((size_t)2 << 23);
  u16* lqB = projout + ((size_t)3 << 23);
  u16* lkB = projout + ((size_t)4 << 23);
  u16* lvB = projout + ((size_t)5 << 23);
  float* biasAll = (float*)(w + ((size_t)160 << 20));

  cast_x<<<8192, 256, 0, stream>>>(x, xb);
  tcast6<<<dim3(64, 64, 6), 256, 0, stream>>>(Wq, Wk, Wv, Wlq, Wlk, Wlv, WtAll);
  const float* bs[6] = {bq, bk, bv, blq, blk, blv};
  for (int i = 0; i < 6; ++i)
    hipMemcpyAsync(biasAll + i * 2048, bs[i], 2048 * sizeof(float),
                   hipMemcpyDeviceToDevice, stream);

  gemm_bt<0><<<dim3(32, 96), 256, 0, stream>>>(xb, WtAll, biasAll, projout);

  vtrans<<<dim3(64, 4, 32), 256, 0, stream>>>(vB, vtB);
  vtrans<<<dim3(64, 4, 32), 256, 0, stream>>>(lvB, lvtB);

  attn_kernel<false><<<dim3(16, 32), 256, 0, stream>>>(qB, kB, vtB, qB);    // O in-place over Q
  attn_kernel<true><<<dim3(16, 32), 256, 0, stream>>>(lqB, lkB, lvtB, lqB);

  mix_kernel<<<4096, 256, 0, stream>>>(qB, lqB, gmask, xb);

  tcast<<<dim3(64, 64), 256, 0, stream>>>(Wp, wtP);
  gemm_bt<1><<<dim3(32, 16), 256, 0, stream>>>(xb, wtP, bp, out);
}